// Round 7
// baseline (2338.691 us; speedup 1.0000x reference)
//
#include <hip/hip_runtime.h>
#include <hip/hip_fp8.h>
#include <cstdio>
#include <cstdint>

#define K_DIM 4096
#define N_DIM 4096
#define BKB 64                 // K-bytes per LDS tile
#define NT (K_DIM / BKB)       // 64 K-tiles

typedef int v4i __attribute__((ext_vector_type(4)));
typedef int v8i __attribute__((ext_vector_type(8)));
typedef float v16f __attribute__((ext_vector_type(16)));

// ---------------------------------------------------------------- amax ------
__global__ void amax_kernel(const float4* __restrict__ x, int n4,
                            unsigned* __restrict__ out) {
  int i = blockIdx.x * blockDim.x + threadIdx.x;
  int stride = gridDim.x * blockDim.x;
  float m = 0.f;
  for (; i < n4; i += stride) {
    float4 v = x[i];
    m = fmaxf(m, fmaxf(fmaxf(fabsf(v.x), fabsf(v.y)),
                       fmaxf(fabsf(v.z), fabsf(v.w))));
  }
#pragma unroll
  for (int off = 32; off > 0; off >>= 1)
    m = fmaxf(m, __shfl_down(m, off, 64));
  __shared__ float wred[4];
  int lane = threadIdx.x & 63, wid = threadIdx.x >> 6;
  if (lane == 0) wred[wid] = m;
  __syncthreads();
  if (threadIdx.x == 0) {
    m = fmaxf(fmaxf(wred[0], wred[1]), fmaxf(wred[2], wred[3]));
    atomicMax(out, __float_as_uint(m));  // bit-compare valid: m >= 0
  }
}

__device__ __forceinline__ float load_scale(const unsigned* p) {
  return fmaxf(__uint_as_float(*p) / 448.0f, 1e-12f);
}

__device__ __forceinline__ unsigned f2fp8(float v) {
  return (unsigned)__hip_cvt_float_to_fp8(v, __HIP_SATFINITE, __HIP_E4M3);
}

// ------------------------------------------------------------- quantize A ---
__global__ void quant1_kernel(const float4* __restrict__ x, uint4* __restrict__ q,
                              const unsigned* __restrict__ amax_bits, int n16) {
  float s = load_scale(amax_bits);
  int i = blockIdx.x * blockDim.x + threadIdx.x;
  int stride = gridDim.x * blockDim.x;
  for (; i < n16; i += stride) {
    unsigned w[4];
#pragma unroll
    for (int j = 0; j < 4; ++j) {
      float4 v = x[i * 4 + j];
      w[j] = f2fp8(v.x / s) | (f2fp8(v.y / s) << 8) |
             (f2fp8(v.z / s) << 16) | (f2fp8(v.w / s) << 24);
    }
    uint4 r; r.x = w[0]; r.y = w[1]; r.z = w[2]; r.w = w[3];
    q[i] = r;
  }
}

// ---------------------------- quantize B -> MFMA-fragment-blocked layout ----
// x: [K][N] fp32 -> Bq[n32][k64][lane][32B]: chunk (n32,k64) is the 2048-B
// fragment a wave consumes for B-subtile n32 at K-tile k64: lane l = kh*32+r5
// holds Bt[n32*32+r5][k64*64 + kh*32 .. +31]. Wave load = base + lane*32.
__global__ void quant2t_kernel(const float* __restrict__ x,
                               unsigned char* __restrict__ qt,
                               const unsigned* __restrict__ amax_bits) {
  float s = load_scale(amax_bits);
  __shared__ unsigned char tile[64][68];
  int tj = blockIdx.x & 63;   // N tile (2 chunks of 32)
  int ti = blockIdx.x >> 6;   // K tile
  int t = threadIdx.x;
  int c = t & 63;
  int r0 = (t >> 6) * 16;
#pragma unroll
  for (int rr = 0; rr < 16; ++rr) {
    int r = r0 + rr;
    float v = x[(size_t)(ti * 64 + r) * N_DIM + tj * 64 + c];
    tile[c][r] = (unsigned char)f2fp8(v / s);  // tile[n][k]
  }
  __syncthreads();
  int n = t >> 2;             // 0..63
  int kc = (t & 3) << 4;      // 0,16,32,48
  const unsigned* lp = (const unsigned*)&tile[n][kc];
  uint4 v; v.x = lp[0]; v.y = lp[1]; v.z = lp[2]; v.w = lp[3];
  int n32 = tj * 2 + (n >> 5);
  size_t dst = ((size_t)n32 * 64 + ti) * 2048 +
               (size_t)(((kc >> 5) * 32 + (n & 31)) * 32 + (kc & 31));
  *(uint4*)&qt[dst] = v;
}

// ------------------------------------------------------------------ GEMM ----
// 128x256 tile, 8 waves (2Mx4N), wave owns 64x64, BK=64B, MX-scaled fp8 MFMA
// (scale exp 127 = exact 1.0) at 2x non-scaled rate.
// KEY CHANGE vs r6: per-wave register footprint cut to ~124 (acc 64 + b 16 +
// bn 16 + a 16 + addr) with __launch_bounds__(512,4) -> TWO independent
// blocks/CU (4 waves/SIMD, 2 barrier domains) so one block's MFMA clusters
// cover the other's mem phases. No register rotation (unroll-by-2 swaps b/bn
// statically); A-frags read just-in-time (compiler schedules lgkm waits).
// A: LDS ring-4 x 8KB via global_load_lds (linear dest, pre-swizzled source),
//    staged 3 tiles ahead. B: global->register from fragment-blocked Bq.
#define GLOAD(src, dst)                                              \
  __builtin_amdgcn_global_load_lds(                                  \
      (const __attribute__((address_space(1))) void*)(src),          \
      (__attribute__((address_space(3))) void*)(dst), 16, 0, 0)

#define MFMA_SC(a, b, c)                                             \
  __builtin_amdgcn_mfma_scale_f32_32x32x64_f8f6f4(a, b, c, 0, 0, 0, 127, 0, 127)

__global__ __launch_bounds__(512, 4)
void gemm_fp8_kernel(const unsigned char* __restrict__ A,
                     const unsigned char* __restrict__ Bq,
                     float* __restrict__ C,
                     const unsigned* __restrict__ amax_bits) {
  __shared__ __align__(16) unsigned char lds[4][8192];

  int bid = blockIdx.x;
  int nwg = gridDim.x;                    // 2048, %8 == 0
  int swz = (bid & 7) * (nwg >> 3) + (bid >> 3);
  int brow = (swz >> 4) * 128;            // 128 row tiles
  int bcol = (swz & 15) * 256;            // 16 col tiles

  int t = threadIdx.x;
  int lane = t & 63, wid = t >> 6;
  int wm = wid >> 2, wn = wid & 3;        // wave quadrant: 2M x 4N
  int r5 = lane & 31;
  int khalf = lane >> 5;

  // A staging: one gload/thread/tile; dest linear t*16, source pre-swizzled.
  int su = (t & 7) ^ ((t >> 3) & 7);
  int srow = 2 * (t >> 3) + (su >> 2);    // 0..127
  int scol = (su & 3) << 4;
  int sdst = t << 4;
  const unsigned char* gA = A + (size_t)(brow + srow) * K_DIM + scol;

  // B direct: wave's two chunks for tile T at gB + {0,131072} + T*2048 + lane*32
  const unsigned char* gB =
      Bq + ((size_t)((bcol >> 5) + wn * 2) * 64) * 2048 + (size_t)lane * 32;

  // A fragment reads: row = wm*64 + m*32 + r5 -> (wm*32 + (r5>>1))*128 +
  // m*2048 + swizzled slot; bytes khalf*32..+31 as two b128.
  int kq0 = khalf << 1;
  int mac = (r5 >> 1) & 7;
  int slot0 = (((((r5 & 1) << 2) | kq0) ^ mac) << 4);
  int slot1 = (((((r5 & 1) << 2) | (kq0 + 1)) ^ mac) << 4);
  int arow = (wm * 32 + (r5 >> 1)) * 128;   // + m*2048 per subtile

  auto STAGE = [&](int T) {
    unsigned char* dst = &lds[T & 3][0] + sdst;
    GLOAD(gA + T * BKB, dst);
  };

  auto FRAG = [&](const unsigned char* buf, int base) -> v8i {
    v4i lo = *(const v4i*)(buf + base + slot0);
    v4i hi = *(const v4i*)(buf + base + slot1);
    return __builtin_shufflevector(lo, hi, 0, 1, 2, 3, 4, 5, 6, 7);
  };

  auto BFRAG = [&](int n, int T) -> v8i {
    const v4i* p = (const v4i*)(gB + (size_t)n * 131072 + (size_t)T * 2048);
    v4i lo = p[0];
    v4i hi = p[1];
    return __builtin_shufflevector(lo, hi, 0, 1, 2, 3, 4, 5, 6, 7);
  };

  v16f acc00 = {}, acc01 = {}, acc10 = {}, acc11 = {};

  // prologue: stage A tiles 0,1,2; load B(0); drain once; barrier.
  STAGE(0); STAGE(1); STAGE(2);
  v8i bA0 = BFRAG(0, 0), bA1 = BFRAG(1, 0);
  asm volatile("s_waitcnt vmcnt(0)" ::: "memory");
  __builtin_amdgcn_s_barrier();

  // One K-tile: B loads for T+1 into bn (used next call -> no rotation movs
  // thanks to unroll-by-2 swapping roles), stage T+3, JIT A-frag reads, 4
  // MFMA, then counted-vmcnt boundary + barrier while staging continues.
  auto TILE = [&](int T, v8i& b0, v8i& b1, v8i& bn0, v8i& bn1) {
    bool st = (T + 3) < NT;
    if ((T + 1) < NT) { bn0 = BFRAG(0, T + 1); bn1 = BFRAG(1, T + 1); }
    if (st) STAGE(T + 3);

    const unsigned char* buf = lds[T & 3];
    v8i a0 = FRAG(buf, arow);
    v8i a1 = FRAG(buf, arow + 2048);

    __builtin_amdgcn_s_setprio(1);
    acc00 = MFMA_SC(a0, b0, acc00);
    acc01 = MFMA_SC(a0, b1, acc01);
    acc10 = MFMA_SC(a1, b0, acc10);
    acc11 = MFMA_SC(a1, b1, acc11);
    __builtin_amdgcn_s_setprio(0);

    // boundary: keep this iter's 5 VMEM (4 B-loads + 1 stage) in flight;
    // everything older (incl. stage(T+2)) retired -> ring slot publish is
    // one tile early (safe). vmcnt(4) at NT-3 drains the final stage.
    if (st) {
      asm volatile("s_waitcnt vmcnt(5)" ::: "memory");
      __builtin_amdgcn_s_barrier();
    } else if (T == NT - 3) {
      asm volatile("s_waitcnt vmcnt(4)" ::: "memory");
      __builtin_amdgcn_s_barrier();
    }
    // T >= NT-2: no staging remains; no barrier needed.
  };

  v8i bB0, bB1;
  for (int T = 0; T < NT; T += 2) {
    TILE(T, bA0, bA1, bB0, bB1);
    TILE(T + 1, bB0, bB1, bA0, bA1);
  }

  // epilogue: 32x32 C/D map: col = lane&31, row = (reg&3)+8*(reg>>2)+4*(lane>>5)
  float scale = load_scale(amax_bits) * load_scale(amax_bits + 1);
  float* Cp = C + (size_t)(brow + wm * 64 + khalf * 4) * N_DIM +
              (bcol + wn * 64 + r5);
  const v16f* accp[2][2] = {{&acc00, &acc01}, {&acc10, &acc11}};
#pragma unroll
  for (int m = 0; m < 2; ++m)
#pragma unroll
    for (int r = 0; r < 16; ++r) {
      size_t ro = (size_t)(m * 32 + (r & 3) + 8 * (r >> 2)) * N_DIM;
#pragma unroll
      for (int n = 0; n < 2; ++n)
        Cp[ro + n * 32] = (*accp[m][n])[r] * scale;
    }
}

// ----------------------------------------------------------------- launch ---
extern "C" void kernel_launch(void* const* d_in, const int* in_sizes, int n_in,
                              void* d_out, int out_size, void* d_ws,
                              size_t ws_size, hipStream_t stream) {
  const float* in1 = (const float*)d_in[0];
  const float* in2 = (const float*)d_in[1];
  float* out = (float*)d_out;
  unsigned char* ws = (unsigned char*)d_ws;

  const int R = in_sizes[0] / K_DIM;  // 16384
  const size_t qa_bytes = (size_t)R * K_DIM;
  const size_t qb_bytes = (size_t)N_DIM * K_DIM;
  const size_t need = 256 + qa_bytes + qb_bytes;
  if (ws_size < need) {
    fprintf(stderr, "kernel_launch: ws_size %zu < needed %zu\n", ws_size, need);
    return;
  }
  unsigned* amax = (unsigned*)ws;
  unsigned char* q1 = ws + 256;
  unsigned char* q2t = q1 + qa_bytes;

  hipMemsetAsync(ws, 0, 8, stream);
  amax_kernel<<<2048, 256, 0, stream>>>((const float4*)in1, in_sizes[0] / 4, amax);
  amax_kernel<<<1024, 256, 0, stream>>>((const float4*)in2, in_sizes[1] / 4, amax + 1);
  quant1_kernel<<<2048, 256, 0, stream>>>((const float4*)in1, (uint4*)q1, amax,
                                          in_sizes[0] / 16);
  quant2t_kernel<<<(K_DIM / 64) * (N_DIM / 64), 256, 0, stream>>>(in2, q2t, amax + 1);
  gemm_fp8_kernel<<<(R / 128) * (N_DIM / 256), 512, 0, stream>>>(q1, q2t, out, amax);
}

// Round 8
// 2105.574 us; speedup vs baseline: 1.1107x; 1.1107x over previous
//
#include <hip/hip_runtime.h>
#include <hip/hip_fp8.h>
#include <cstdio>
#include <cstdint>

#define K_DIM 4096
#define N_DIM 4096
#define BKB 64                 // K-bytes per LDS tile
#define NT (K_DIM / BKB)       // 64 K-tiles

typedef int v4i __attribute__((ext_vector_type(4)));
typedef int v8i __attribute__((ext_vector_type(8)));
typedef float v16f __attribute__((ext_vector_type(16)));

// ---------------------------------------------------------------- amax ------
__global__ void amax_kernel(const float4* __restrict__ x, int n4,
                            unsigned* __restrict__ out) {
  int i = blockIdx.x * blockDim.x + threadIdx.x;
  int stride = gridDim.x * blockDim.x;
  float m = 0.f;
  for (; i < n4; i += stride) {
    float4 v = x[i];
    m = fmaxf(m, fmaxf(fmaxf(fabsf(v.x), fabsf(v.y)),
                       fmaxf(fabsf(v.z), fabsf(v.w))));
  }
#pragma unroll
  for (int off = 32; off > 0; off >>= 1)
    m = fmaxf(m, __shfl_down(m, off, 64));
  __shared__ float wred[4];
  int lane = threadIdx.x & 63, wid = threadIdx.x >> 6;
  if (lane == 0) wred[wid] = m;
  __syncthreads();
  if (threadIdx.x == 0) {
    m = fmaxf(fmaxf(wred[0], wred[1]), fmaxf(wred[2], wred[3]));
    atomicMax(out, __float_as_uint(m));  // bit-compare valid: m >= 0
  }
}

__device__ __forceinline__ float load_scale(const unsigned* p) {
  return fmaxf(__uint_as_float(*p) / 448.0f, 1e-12f);
}

__device__ __forceinline__ unsigned f2fp8(float v) {
  return (unsigned)__hip_cvt_float_to_fp8(v, __HIP_SATFINITE, __HIP_E4M3);
}

// ------------------------------------------------------------- quantize A ---
__global__ void quant1_kernel(const float4* __restrict__ x, uint4* __restrict__ q,
                              const unsigned* __restrict__ amax_bits, int n16) {
  float s = load_scale(amax_bits);
  int i = blockIdx.x * blockDim.x + threadIdx.x;
  int stride = gridDim.x * blockDim.x;
  for (; i < n16; i += stride) {
    unsigned w[4];
#pragma unroll
    for (int j = 0; j < 4; ++j) {
      float4 v = x[i * 4 + j];
      w[j] = f2fp8(v.x / s) | (f2fp8(v.y / s) << 8) |
             (f2fp8(v.z / s) << 16) | (f2fp8(v.w / s) << 24);
    }
    uint4 r; r.x = w[0]; r.y = w[1]; r.z = w[2]; r.w = w[3];
    q[i] = r;
  }
}

// ---------------------------- quantize B -> MFMA-fragment-blocked layout ----
// x: [K][N] fp32 -> Bq[n32][k64][lane][32B]: chunk (n32,k64) is the 2048-B
// fragment a wave consumes for B-subtile n32 at K-tile k64: lane l = kh*32+r5
// holds Bt[n32*32+r5][k64*64 + kh*32 .. +31]. Wave load = base + lane*32.
__global__ void quant2t_kernel(const float* __restrict__ x,
                               unsigned char* __restrict__ qt,
                               const unsigned* __restrict__ amax_bits) {
  float s = load_scale(amax_bits);
  __shared__ unsigned char tile[64][68];
  int tj = blockIdx.x & 63;   // N tile (2 chunks of 32)
  int ti = blockIdx.x >> 6;   // K tile
  int t = threadIdx.x;
  int c = t & 63;
  int r0 = (t >> 6) * 16;
#pragma unroll
  for (int rr = 0; rr < 16; ++rr) {
    int r = r0 + rr;
    float v = x[(size_t)(ti * 64 + r) * N_DIM + tj * 64 + c];
    tile[c][r] = (unsigned char)f2fp8(v / s);  // tile[n][k]
  }
  __syncthreads();
  int n = t >> 2;             // 0..63
  int kc = (t & 3) << 4;      // 0,16,32,48
  const unsigned* lp = (const unsigned*)&tile[n][kc];
  uint4 v; v.x = lp[0]; v.y = lp[1]; v.z = lp[2]; v.w = lp[3];
  int n32 = tj * 2 + (n >> 5);
  size_t dst = ((size_t)n32 * 64 + ti) * 2048 +
               (size_t)(((kc >> 5) * 32 + (n & 31)) * 32 + (kc & 31));
  *(uint4*)&qt[dst] = v;
}

// ------------------------------------------------------------------ GEMM ----
// 128x256 tile, 8 waves (2Mx4N), wave owns 64x64, BK=64B, MX-scaled fp8 MFMA
// (scale exp 127 = exact 1.0) at 2x non-scaled rate.
// vs r7: B prefetch/rotation REMOVED so regs fit the (512,4) budget:
// acc 64 AGPR + ~50 VGPR < 128 -> genuinely 2 blocks/CU (4 waves/SIMD, two
// barrier domains in anti-phase; one block's MFMA covers the other's mem
// phase). B is JIT global->reg (issued at iter top AFTER nothing: B first,
// stage after -> compiler's B-wait never drains the fresh stage). No manual
// boundary vmcnt: per-wave dataflow waits already retire stage(T+1) one full
// iter early; the per-iter barrier publishes it.
// A: LDS ring-4 x 8KB via global_load_lds (linear dest, pre-swizzled source),
//    staged 3 tiles ahead. B: fragment-blocked Bq, L1/L2-resident.
#define GLOAD(src, dst)                                              \
  __builtin_amdgcn_global_load_lds(                                  \
      (const __attribute__((address_space(1))) void*)(src),          \
      (__attribute__((address_space(3))) void*)(dst), 16, 0, 0)

#define MFMA_SC(a, b, c)                                             \
  __builtin_amdgcn_mfma_scale_f32_32x32x64_f8f6f4(a, b, c, 0, 0, 0, 127, 0, 127)

__global__ __launch_bounds__(512, 4)
void gemm_fp8_kernel(const unsigned char* __restrict__ A,
                     const unsigned char* __restrict__ Bq,
                     float* __restrict__ C,
                     const unsigned* __restrict__ amax_bits) {
  __shared__ __align__(16) unsigned char lds[4][8192];

  int bid = blockIdx.x;
  int nwg = gridDim.x;                    // 2048, %8 == 0
  int swz = (bid & 7) * (nwg >> 3) + (bid >> 3);
  int brow = (swz >> 4) * 128;            // 128 row tiles
  int bcol = (swz & 15) * 256;            // 16 col tiles

  int t = threadIdx.x;
  int lane = t & 63, wid = t >> 6;
  int wm = wid >> 2, wn = wid & 3;        // wave quadrant: 2M x 4N
  int r5 = lane & 31;
  int khalf = lane >> 5;

  // A staging: one gload/thread/tile; dest linear t*16, source pre-swizzled.
  int su = (t & 7) ^ ((t >> 3) & 7);
  int srow = 2 * (t >> 3) + (su >> 2);    // 0..127
  int scol = (su & 3) << 4;
  int sdst = t << 4;
  const unsigned char* gA = A + (size_t)(brow + srow) * K_DIM + scol;

  // B direct: wave's two chunks for tile T at gB + {0,131072} + T*2048 + lane*32
  const unsigned char* gB =
      Bq + ((size_t)((bcol >> 5) + wn * 2) * 64) * 2048 + (size_t)lane * 32;

  // A fragment reads: row = wm*64 + m*32 + r5 -> (wm*32 + (r5>>1))*128 +
  // m*2048 + swizzled slot; bytes khalf*32..+31 as two b128.
  int kq0 = khalf << 1;
  int mac = (r5 >> 1) & 7;
  int slot0 = (((((r5 & 1) << 2) | kq0) ^ mac) << 4);
  int slot1 = (((((r5 & 1) << 2) | (kq0 + 1)) ^ mac) << 4);
  int arow = (wm * 32 + (r5 >> 1)) * 128;   // + m*2048 per subtile

  auto STAGE = [&](int T) {
    unsigned char* dst = &lds[T & 3][0] + sdst;
    GLOAD(gA + T * BKB, dst);
  };

  auto FRAG = [&](const unsigned char* buf, int base) -> v8i {
    v4i lo = *(const v4i*)(buf + base + slot0);
    v4i hi = *(const v4i*)(buf + base + slot1);
    return __builtin_shufflevector(lo, hi, 0, 1, 2, 3, 4, 5, 6, 7);
  };

  auto BFRAG = [&](int n, int T) -> v8i {
    const v4i* p = (const v4i*)(gB + (size_t)n * 131072 + (size_t)T * 2048);
    v4i lo = p[0];
    v4i hi = p[1];
    return __builtin_shufflevector(lo, hi, 0, 1, 2, 3, 4, 5, 6, 7);
  };

  v16f acc00 = {}, acc01 = {}, acc10 = {}, acc11 = {};

  // prologue: stage A tiles 0,1,2; wait stage(0); barrier.
  STAGE(0); STAGE(1); STAGE(2);
  asm volatile("s_waitcnt vmcnt(2)" ::: "memory");
  __builtin_amdgcn_s_barrier();

  for (int T = 0; T < NT; ++T) {
    // B loads first (oldest in queue) so the compiler's pre-MFMA wait for
    // b0/b1 leaves the just-issued stage in flight.
    v8i b0 = BFRAG(0, T);
    v8i b1 = BFRAG(1, T);
    if (T + 3 < NT) STAGE(T + 3);

    const unsigned char* buf = lds[T & 3];
    v8i a0 = FRAG(buf, arow);
    v8i a1 = FRAG(buf, arow + 2048);

    __builtin_amdgcn_s_setprio(1);
    acc00 = MFMA_SC(a0, b0, acc00);
    acc01 = MFMA_SC(a0, b1, acc01);
    acc10 = MFMA_SC(a1, b0, acc10);
    acc11 = MFMA_SC(a1, b1, acc11);
    __builtin_amdgcn_s_setprio(0);

    // Publish slot T+1 (its data retired a full iter ago via this wave's own
    // b-load waits) and protect slot (T-1)&3 == (T+3)&3 from next iter's
    // staging until all waves' reads of it retired (their MFMA lgkm waits).
    if (T + 1 < NT) __builtin_amdgcn_s_barrier();
  }

  // epilogue: 32x32 C/D map: col = lane&31, row = (reg&3)+8*(reg>>2)+4*(lane>>5)
  float scale = load_scale(amax_bits) * load_scale(amax_bits + 1);
  float* Cp = C + (size_t)(brow + wm * 64 + khalf * 4) * N_DIM +
              (bcol + wn * 64 + r5);
  const v16f* accp[2][2] = {{&acc00, &acc01}, {&acc10, &acc11}};
#pragma unroll
  for (int m = 0; m < 2; ++m)
#pragma unroll
    for (int r = 0; r < 16; ++r) {
      size_t ro = (size_t)(m * 32 + (r & 3) + 8 * (r >> 2)) * N_DIM;
#pragma unroll
      for (int n = 0; n < 2; ++n)
        Cp[ro + n * 32] = (*accp[m][n])[r] * scale;
    }
}

// ----------------------------------------------------------------- launch ---
extern "C" void kernel_launch(void* const* d_in, const int* in_sizes, int n_in,
                              void* d_out, int out_size, void* d_ws,
                              size_t ws_size, hipStream_t stream) {
  const float* in1 = (const float*)d_in[0];
  const float* in2 = (const float*)d_in[1];
  float* out = (float*)d_out;
  unsigned char* ws = (unsigned char*)d_ws;

  const int R = in_sizes[0] / K_DIM;  // 16384
  const size_t qa_bytes = (size_t)R * K_DIM;
  const size_t qb_bytes = (size_t)N_DIM * K_DIM;
  const size_t need = 256 + qa_bytes + qb_bytes;
  if (ws_size < need) {
    fprintf(stderr, "kernel_launch: ws_size %zu < needed %zu\n", ws_size, need);
    return;
  }
  unsigned* amax = (unsigned*)ws;
  unsigned char* q1 = ws + 256;
  unsigned char* q2t = q1 + qa_bytes;

  hipMemsetAsync(ws, 0, 8, stream);
  amax_kernel<<<2048, 256, 0, stream>>>((const float4*)in1, in_sizes[0] / 4, amax);
  amax_kernel<<<1024, 256, 0, stream>>>((const float4*)in2, in_sizes[1] / 4, amax + 1);
  quant1_kernel<<<2048, 256, 0, stream>>>((const float4*)in1, (uint4*)q1, amax,
                                          in_sizes[0] / 16);
  quant2t_kernel<<<(K_DIM / 64) * (N_DIM / 64), 256, 0, stream>>>(in2, q2t, amax + 1);
  gemm_fp8_kernel<<<(R / 128) * (N_DIM / 256), 512, 0, stream>>>(q1, q2t, out, amax);
}

// Round 9
// 548.907 us; speedup vs baseline: 4.2606x; 3.8359x over previous
//
#include <hip/hip_runtime.h>
#include <hip/hip_fp8.h>
#include <cstdio>
#include <cstdint>

#define K_DIM 4096
#define N_DIM 4096
#define BKB 64                 // K-bytes per LDS tile
#define NT (K_DIM / BKB)       // 64 K-tiles

typedef int v4i __attribute__((ext_vector_type(4)));
typedef int v8i __attribute__((ext_vector_type(8)));
typedef float v16f __attribute__((ext_vector_type(16)));

// ---------------------------------------------------------------- amax ------
__global__ void amax_kernel(const float4* __restrict__ x, int n4,
                            unsigned* __restrict__ out) {
  int i = blockIdx.x * blockDim.x + threadIdx.x;
  int stride = gridDim.x * blockDim.x;
  float m = 0.f;
  for (; i < n4; i += stride) {
    float4 v = x[i];
    m = fmaxf(m, fmaxf(fmaxf(fabsf(v.x), fabsf(v.y)),
                       fmaxf(fabsf(v.z), fabsf(v.w))));
  }
#pragma unroll
  for (int off = 32; off > 0; off >>= 1)
    m = fmaxf(m, __shfl_down(m, off, 64));
  __shared__ float wred[4];
  int lane = threadIdx.x & 63, wid = threadIdx.x >> 6;
  if (lane == 0) wred[wid] = m;
  __syncthreads();
  if (threadIdx.x == 0) {
    m = fmaxf(fmaxf(wred[0], wred[1]), fmaxf(wred[2], wred[3]));
    atomicMax(out, __float_as_uint(m));  // bit-compare valid: m >= 0
  }
}

__device__ __forceinline__ float load_scale(const unsigned* p) {
  return fmaxf(__uint_as_float(*p) / 448.0f, 1e-12f);
}

__device__ __forceinline__ unsigned f2fp8(float v) {
  return (unsigned)__hip_cvt_float_to_fp8(v, __HIP_SATFINITE, __HIP_E4M3);
}

// ------------------------------------------------------------- quantize A ---
__global__ void quant1_kernel(const float4* __restrict__ x, uint4* __restrict__ q,
                              const unsigned* __restrict__ amax_bits, int n16) {
  float s = load_scale(amax_bits);
  int i = blockIdx.x * blockDim.x + threadIdx.x;
  int stride = gridDim.x * blockDim.x;
  for (; i < n16; i += stride) {
    unsigned w[4];
#pragma unroll
    for (int j = 0; j < 4; ++j) {
      float4 v = x[i * 4 + j];
      w[j] = f2fp8(v.x / s) | (f2fp8(v.y / s) << 8) |
             (f2fp8(v.z / s) << 16) | (f2fp8(v.w / s) << 24);
    }
    uint4 r; r.x = w[0]; r.y = w[1]; r.z = w[2]; r.w = w[3];
    q[i] = r;
  }
}

// ---------------------------- quantize B -> MFMA-fragment-blocked layout ----
// x: [K][N] fp32 -> Bq[n32][k64][lane][32B]: chunk (n32,k64) is the 2048-B
// fragment a wave consumes for B-subtile n32 at K-tile k64: lane l = kh*32+r5
// holds Bt[n32*32+r5][k64*64 + kh*32 .. +31]. Wave load = base + lane*32.
__global__ void quant2t_kernel(const float* __restrict__ x,
                               unsigned char* __restrict__ qt,
                               const unsigned* __restrict__ amax_bits) {
  float s = load_scale(amax_bits);
  __shared__ unsigned char tile[64][68];
  int tj = blockIdx.x & 63;   // N tile (2 chunks of 32)
  int ti = blockIdx.x >> 6;   // K tile
  int t = threadIdx.x;
  int c = t & 63;
  int r0 = (t >> 6) * 16;
#pragma unroll
  for (int rr = 0; rr < 16; ++rr) {
    int r = r0 + rr;
    float v = x[(size_t)(ti * 64 + r) * N_DIM + tj * 64 + c];
    tile[c][r] = (unsigned char)f2fp8(v / s);  // tile[n][k]
  }
  __syncthreads();
  int n = t >> 2;             // 0..63
  int kc = (t & 3) << 4;      // 0,16,32,48
  const unsigned* lp = (const unsigned*)&tile[n][kc];
  uint4 v; v.x = lp[0]; v.y = lp[1]; v.z = lp[2]; v.w = lp[3];
  int n32 = tj * 2 + (n >> 5);
  size_t dst = ((size_t)n32 * 64 + ti) * 2048 +
               (size_t)(((kc >> 5) * 32 + (n & 31)) * 32 + (kc & 31));
  *(uint4*)&qt[dst] = v;
}

// ------------------------------------------------------------------ GEMM ----
// 128x128 tile, 4 waves (2Mx2N, 1 wave/SIMD), wave owns 64x64, BK=64B,
// MX-scaled fp8 MFMA (scale exp 127 = exact 1.0) at 2x non-scaled rate.
// REGISTER GEOMETRY (the r7/r8 lesson): unified file = 512 regs/wave-slot.
// __launch_bounds__(256,3) -> 170 total regs/wave -> 3 BLOCKS/CU (3 waves/
// SIMD, three anti-phased barrier domains). Budget: acc 64 + a 16 + b 16 +
// bn 16 + addr ~15 ~= 130 < 170 -> no spill, B prefetch restored.
// A: LDS ring-4 x 8KB via global_load_lds (linear dest, pre-swizzled source),
//    staged 3 tiles ahead (2 gloads/thread/tile).
// B: fragment-blocked Bq, global->reg one tile ahead (L1/L2-resident),
//    unroll-2 static role swap (no rotation movs).
// SYNC: one raw s_barrier per iter, NO manual loop vmcnt. Dataflow proof:
// B(T)'s pre-MFMA vmcnt at iter T also retires stage(T+1) (older in queue)
// on the writer wave, so the end-of-T barrier publishes slot T+1 to readers
// at iter T+1. Slot overwrite (T+3 = T-1 mod 4) is behind the same barrier.
#define GLOAD(src, dst)                                              \
  __builtin_amdgcn_global_load_lds(                                  \
      (const __attribute__((address_space(1))) void*)(src),          \
      (__attribute__((address_space(3))) void*)(dst), 16, 0, 0)

#define MFMA_SC(a, b, c)                                             \
  __builtin_amdgcn_mfma_scale_f32_32x32x64_f8f6f4(a, b, c, 0, 0, 0, 127, 0, 127)

__global__ __launch_bounds__(256, 3)
void gemm_fp8_kernel(const unsigned char* __restrict__ A,
                     const unsigned char* __restrict__ Bq,
                     float* __restrict__ C,
                     const unsigned* __restrict__ amax_bits) {
  __shared__ __align__(16) unsigned char lds[4][8192];

  int bid = blockIdx.x;
  int nwg = gridDim.x;                    // 4096, %8 == 0
  int swz = (bid & 7) * (nwg >> 3) + (bid >> 3);
  int brow = (swz >> 5) * 128;            // 128 row tiles
  int bcol = (swz & 31) * 128;            // 32 col tiles

  int t = threadIdx.x;
  int lane = t & 63, wid = t >> 6;
  int wm = wid >> 1, wn = wid & 1;        // wave quadrant: 2M x 2N
  int r5 = lane & 31;
  int khalf = lane >> 5;

  // A staging: 2 gloads/thread/tile; dest linear t*16 (+4096), source
  // pre-swizzled. Rows 0..63 chunk0, 64..127 chunk1 (macro%8 identical).
  int su = (t & 7) ^ ((t >> 3) & 7);
  int srow = 2 * (t >> 3) + (su >> 2);    // 0..63
  int scol = (su & 3) << 4;
  int sdst = t << 4;
  const unsigned char* gA0 = A + (size_t)(brow + srow) * K_DIM + scol;
  const unsigned char* gA1 = gA0 + (size_t)64 * K_DIM;

  // B direct: wave's two chunks for tile T at gB + {0,131072} + T*2048 + lane*32
  const unsigned char* gB =
      Bq + ((size_t)((bcol >> 5) + wn * 2) * 64) * 2048 + (size_t)lane * 32;

  // A fragment reads: row = wm*64 + m*32 + r5 -> (wm*32 + m*16 + (r5>>1))*128
  // + swizzled slot; bytes khalf*32..+31 as two b128.
  int kq0 = khalf << 1;
  int mac = (r5 >> 1) & 7;
  int slot0 = (((((r5 & 1) << 2) | kq0) ^ mac) << 4);
  int slot1 = (((((r5 & 1) << 2) | (kq0 + 1)) ^ mac) << 4);
  int arow = (wm * 32 + (r5 >> 1)) * 128;   // + m*2048 per subtile

  auto STAGE = [&](int T) {
    unsigned char* dst = &lds[T & 3][0] + sdst;
    GLOAD(gA0 + T * BKB, dst);
    GLOAD(gA1 + T * BKB, dst + 4096);
  };

  auto FRAG = [&](const unsigned char* buf, int base) -> v8i {
    v4i lo = *(const v4i*)(buf + base + slot0);
    v4i hi = *(const v4i*)(buf + base + slot1);
    return __builtin_shufflevector(lo, hi, 0, 1, 2, 3, 4, 5, 6, 7);
  };

  auto BFRAG = [&](int n, int T) -> v8i {
    const v4i* p = (const v4i*)(gB + (size_t)n * 131072 + (size_t)T * 2048);
    v4i lo = p[0];
    v4i hi = p[1];
    return __builtin_shufflevector(lo, hi, 0, 1, 2, 3, 4, 5, 6, 7);
  };

  v16f acc00 = {}, acc01 = {}, acc10 = {}, acc11 = {};

  // prologue: stage A tiles 0,1,2 (6 gloads); load B(0); drain stages; barrier.
  STAGE(0); STAGE(1); STAGE(2);
  v8i bA0 = BFRAG(0, 0), bA1 = BFRAG(1, 0);
  asm volatile("s_waitcnt vmcnt(4)" ::: "memory");  // B(0)x4 stay in flight
  __builtin_amdgcn_s_barrier();

  // One K-tile. b0/b1 = this tile's B (already in regs); bn0/bn1 = next
  // tile's B, loaded here, consumed next call (static role swap, no movs).
  auto TILE = [&](int T, v8i& b0, v8i& b1, v8i& bn0, v8i& bn1) {
    if (T + 1 < NT) { bn0 = BFRAG(0, T + 1); bn1 = BFRAG(1, T + 1); }
    if (T + 3 < NT) STAGE(T + 3);

    const unsigned char* buf = lds[T & 3];
    v8i a0 = FRAG(buf, arow);
    v8i a1 = FRAG(buf, arow + 2048);

    __builtin_amdgcn_s_setprio(1);
    acc00 = MFMA_SC(a0, b0, acc00);
    acc01 = MFMA_SC(a0, b1, acc01);
    acc10 = MFMA_SC(a1, b0, acc10);
    acc11 = MFMA_SC(a1, b1, acc11);
    __builtin_amdgcn_s_setprio(0);

    if (T + 1 < NT) __builtin_amdgcn_s_barrier();
  };

  v8i bB0, bB1;
  for (int T = 0; T < NT; T += 2) {
    TILE(T, bA0, bA1, bB0, bB1);
    TILE(T + 1, bB0, bB1, bA0, bA1);
  }

  // epilogue: 32x32 C/D map: col = lane&31, row = (reg&3)+8*(reg>>2)+4*(lane>>5)
  float scale = load_scale(amax_bits) * load_scale(amax_bits + 1);
  float* Cp = C + (size_t)(brow + wm * 64 + khalf * 4) * N_DIM +
              (bcol + wn * 64 + r5);
  const v16f* accp[2][2] = {{&acc00, &acc01}, {&acc10, &acc11}};
#pragma unroll
  for (int m = 0; m < 2; ++m)
#pragma unroll
    for (int r = 0; r < 16; ++r) {
      size_t ro = (size_t)(m * 32 + (r & 3) + 8 * (r >> 2)) * N_DIM;
#pragma unroll
      for (int n = 0; n < 2; ++n)
        Cp[ro + n * 32] = (*accp[m][n])[r] * scale;
    }
}

// ----------------------------------------------------------------- launch ---
extern "C" void kernel_launch(void* const* d_in, const int* in_sizes, int n_in,
                              void* d_out, int out_size, void* d_ws,
                              size_t ws_size, hipStream_t stream) {
  const float* in1 = (const float*)d_in[0];
  const float* in2 = (const float*)d_in[1];
  float* out = (float*)d_out;
  unsigned char* ws = (unsigned char*)d_ws;

  const int R = in_sizes[0] / K_DIM;  // 16384
  const size_t qa_bytes = (size_t)R * K_DIM;
  const size_t qb_bytes = (size_t)N_DIM * K_DIM;
  const size_t need = 256 + qa_bytes + qb_bytes;
  if (ws_size < need) {
    fprintf(stderr, "kernel_launch: ws_size %zu < needed %zu\n", ws_size, need);
    return;
  }
  unsigned* amax = (unsigned*)ws;
  unsigned char* q1 = ws + 256;
  unsigned char* q2t = q1 + qa_bytes;

  hipMemsetAsync(ws, 0, 8, stream);
  amax_kernel<<<2048, 256, 0, stream>>>((const float4*)in1, in_sizes[0] / 4, amax);
  amax_kernel<<<1024, 256, 0, stream>>>((const float4*)in2, in_sizes[1] / 4, amax + 1);
  quant1_kernel<<<2048, 256, 0, stream>>>((const float4*)in1, (uint4*)q1, amax,
                                          in_sizes[0] / 16);
  quant2t_kernel<<<(K_DIM / 64) * (N_DIM / 64), 256, 0, stream>>>(in2, q2t, amax + 1);
  gemm_fp8_kernel<<<(R / 128) * (N_DIM / 128), 256, 0, stream>>>(q1, q2t, out, amax);
}

// Round 10
// 470.017 us; speedup vs baseline: 4.9758x; 1.1678x over previous
//
#include <hip/hip_runtime.h>
#include <hip/hip_fp8.h>
#include <cstdio>
#include <cstdint>

#define K_DIM 4096
#define N_DIM 4096
#define BKB 64                 // K-bytes per LDS tile
#define NT (K_DIM / BKB)       // 64 K-tiles

typedef int v4i __attribute__((ext_vector_type(4)));
typedef int v8i __attribute__((ext_vector_type(8)));
typedef float v16f __attribute__((ext_vector_type(16)));

// ---------------------------------------------------------------- amax ------
__global__ void amax_kernel(const float4* __restrict__ x, int n4,
                            unsigned* __restrict__ out) {
  int i = blockIdx.x * blockDim.x + threadIdx.x;
  int stride = gridDim.x * blockDim.x;
  float m = 0.f;
  for (; i < n4; i += stride) {
    float4 v = x[i];
    m = fmaxf(m, fmaxf(fmaxf(fabsf(v.x), fabsf(v.y)),
                       fmaxf(fabsf(v.z), fabsf(v.w))));
  }
#pragma unroll
  for (int off = 32; off > 0; off >>= 1)
    m = fmaxf(m, __shfl_down(m, off, 64));
  __shared__ float wred[4];
  int lane = threadIdx.x & 63, wid = threadIdx.x >> 6;
  if (lane == 0) wred[wid] = m;
  __syncthreads();
  if (threadIdx.x == 0) {
    m = fmaxf(fmaxf(wred[0], wred[1]), fmaxf(wred[2], wred[3]));
    atomicMax(out, __float_as_uint(m));  // bit-compare valid: m >= 0
  }
}

__device__ __forceinline__ float load_scale(const unsigned* p) {
  return fmaxf(__uint_as_float(*p) / 448.0f, 1e-12f);
}

__device__ __forceinline__ unsigned f2fp8(float v) {
  return (unsigned)__hip_cvt_float_to_fp8(v, __HIP_SATFINITE, __HIP_E4M3);
}

// ------------------------------------------------------------- quantize A ---
__global__ void quant1_kernel(const float4* __restrict__ x, uint4* __restrict__ q,
                              const unsigned* __restrict__ amax_bits, int n16) {
  float s = load_scale(amax_bits);
  int i = blockIdx.x * blockDim.x + threadIdx.x;
  int stride = gridDim.x * blockDim.x;
  for (; i < n16; i += stride) {
    unsigned w[4];
#pragma unroll
    for (int j = 0; j < 4; ++j) {
      float4 v = x[i * 4 + j];
      w[j] = f2fp8(v.x / s) | (f2fp8(v.y / s) << 8) |
             (f2fp8(v.z / s) << 16) | (f2fp8(v.w / s) << 24);
    }
    uint4 r; r.x = w[0]; r.y = w[1]; r.z = w[2]; r.w = w[3];
    q[i] = r;
  }
}

// -------------------------------------------- quantize + transpose B --------
// x: [K][N] fp32 -> qt: [N][K] fp8 row-major (GEMM B rows = output cols).
__global__ void quant2t_kernel(const float* __restrict__ x,
                               unsigned char* __restrict__ qt,
                               const unsigned* __restrict__ amax_bits) {
  float s = load_scale(amax_bits);
  __shared__ unsigned char tile[64][68];
  int tj = blockIdx.x & 63;
  int ti = blockIdx.x >> 6;
  int t = threadIdx.x;
  int c = t & 63;
  int r0 = (t >> 6) * 16;
#pragma unroll
  for (int rr = 0; rr < 16; ++rr) {
    int r = r0 + rr;
    float v = x[(size_t)(ti * 64 + r) * N_DIM + tj * 64 + c];
    tile[c][r] = (unsigned char)f2fp8(v / s);
  }
  __syncthreads();
  int n = t >> 2;
  int kc = (t & 3) << 4;
  const unsigned* lp = (const unsigned*)&tile[n][kc];
  uint4 v; v.x = lp[0]; v.y = lp[1]; v.z = lp[2]; v.w = lp[3];
  *(uint4*)&qt[(size_t)(tj * 64 + n) * K_DIM + ti * 64 + kc] = v;
}

// ------------------------------------------------------------------ GEMM ----
// m201-style 4-phase/tile schedule, 256x256 tile, 8 waves (2Mx4N), ring-4 LDS,
// MX-scaled fp8 MFMA (scale exp 127 = exact 1.0).
//
// LDS layout (NEW, conflict-free for the 32x32 b128 pattern): per buffer,
// A then B; each is 8 groups (32 rows) x 2 khalf x 64 slots of 16B.
// Logical slot s = 2*r5 + j  (j = 16B chunk of the lane's 32 B), physical
// p = s ^ ((s>>3)&7) -- an involution (bit3+ unchanged). Reads: lanes'
// (p&7) within every 8-lane service group are a permutation of 0..7 ->
// all 32 banks covered, zero conflicts. Staging: global_load_lds linear
// dest (t*16) + source pre-swizzled by the SAME involution (rule #21).
//
// Schedule per tile (phases p=0..3): {ds_read [ph0: b0,b1,a0 | ph_m: a_m];
// 1x global_load_lds part p of tile T+3; s_barrier; lgkmcnt(0)+sched_barrier;
// setprio(1); MFMA a_m*b0, a_m*b1; setprio(0); s_barrier}. Boundary: counted
// vmcnt(8) once per tile (8 = 2 future tiles' parts in flight); drains 4/0
// only in the last 3 tiles.
#define GLOAD(src, dst)                                              \
  __builtin_amdgcn_global_load_lds(                                  \
      (const __attribute__((address_space(1))) void*)(src),          \
      (__attribute__((address_space(3))) void*)(dst), 16, 0, 0)

#define MFMA_SC(a, b, c)                                             \
  __builtin_amdgcn_mfma_scale_f32_32x32x64_f8f6f4(a, b, c, 0, 0, 0, 127, 0, 127)

#define LGKM0_FENCE()                                  \
  do {                                                 \
    asm volatile("s_waitcnt lgkmcnt(0)" ::: "memory"); \
    __builtin_amdgcn_sched_barrier(0);                 \
  } while (0)

__global__ __launch_bounds__(512, 2)
void gemm_fp8_kernel(const unsigned char* __restrict__ A,
                     const unsigned char* __restrict__ Bt,
                     float* __restrict__ C,
                     const unsigned* __restrict__ amax_bits) {
  __shared__ __align__(16) unsigned char lds[4][32768];

  // XCD supertile map: xcd = bid&7 owns a 4-col x 32-row tile region ->
  // per-XCD B hot set = 4 panels ~ 4MB ~ L2; A stripes shared by 4 cols.
  int bid = blockIdx.x;
  int xcd = bid & 7;
  int j = bid >> 3;                           // 0..127
  int brow = ((xcd >> 2) * 32 + (j >> 2)) * 256;   // 64 row tiles
  int bcol = ((xcd & 3) * 4 + (j & 3)) * 256;      // 16 col tiles

  int t = threadIdx.x;
  int lane = t & 63, wid = t >> 6;
  int wm = wid >> 2, wn = wid & 3;            // wave quadrant: 2M x 4N
  int r5 = lane & 31;
  int khalf = lane >> 5;

  // ---- staging setup: thread t writes dest slot (t&63) of group (t>>7),
  // khalf (t>>6)&1, in part {A0,A1,B0,B1}. Source = involution-unswizzled.
  int tp = t & 63;
  int sX = tp ^ ((tp >> 3) & 7);              // logical slot (involution)
  int r5s = sX >> 1, js = sX & 1;
  int srow = (t >> 7) * 32 + r5s;             // 0..127 within part
  int scol = ((t >> 6) & 1) * 32 + js * 16;
  int sdst = t << 4;                          // linear dest within part
  const unsigned char* gA0 = A + (size_t)(brow + srow) * K_DIM + scol;
  const unsigned char* gA1 = gA0 + (size_t)128 * K_DIM;
  const unsigned char* gB0 = Bt + (size_t)(bcol + srow) * K_DIM + scol;
  const unsigned char* gB1 = gB0 + (size_t)128 * K_DIM;

  // ---- fragment-read setup: lane reads slots p0, p0^1 of its group/khalf.
  int p0 = (2 * r5) ^ ((r5 >> 2) & 7);
  int off0 = khalf * 1024 + p0 * 16;
  int off1 = khalf * 1024 + (p0 ^ 1) * 16;

  auto STAGE = [&](int T, int part) {
    const unsigned char* src = (part == 0   ? gA0
                                : part == 1 ? gA1
                                : part == 2 ? gB0
                                            : gB1) + T * BKB;
    GLOAD(src, &lds[T & 3][part * 8192] + sdst);
  };

  auto FRAG = [&](const unsigned char* buf, int g) -> v8i {
    v4i lo = *(const v4i*)(buf + g * 2048 + off0);
    v4i hi = *(const v4i*)(buf + g * 2048 + off1);
    return __builtin_shufflevector(lo, hi, 0, 1, 2, 3, 4, 5, 6, 7);
  };

  v16f acc[4][2] = {};

  // prologue: stage tiles 0,1,2 (12 gloads); vmcnt(8) -> tile 0 landed; bar.
#pragma unroll
  for (int T = 0; T < 3; ++T)
#pragma unroll
    for (int p = 0; p < 4; ++p) STAGE(T, p);
  asm volatile("s_waitcnt vmcnt(8)" ::: "memory");
  __builtin_amdgcn_s_barrier();

  for (int T = 0; T < NT; ++T) {
    const unsigned char* buf = lds[T & 3];
    bool st = (T + 3) < NT;
    v8i b0, b1, a;

#pragma unroll
    for (int m = 0; m < 4; ++m) {
      // phase m: reads (ph0 also loads b0,b1), stage part m of T+3
      if (m == 0) {
        b0 = FRAG(buf + 16384, wn * 2 + 0);
        b1 = FRAG(buf + 16384, wn * 2 + 1);
      }
      a = FRAG(buf, wm * 4 + m);
      if (st) STAGE(T + 3, m);
      __builtin_amdgcn_s_barrier();
      LGKM0_FENCE();
      __builtin_amdgcn_s_setprio(1);
      acc[m][0] = MFMA_SC(a, b0, acc[m][0]);
      acc[m][1] = MFMA_SC(a, b1, acc[m][1]);
      __builtin_amdgcn_s_setprio(0);
      if (m < 3) __builtin_amdgcn_s_barrier();
    }

    // tile boundary: counted drain (publish tile T+1; never 0 until the end)
    if (T + 3 < NT) {
      asm volatile("s_waitcnt vmcnt(8)" ::: "memory");
    } else if (T + 2 < NT) {
      asm volatile("s_waitcnt vmcnt(4)" ::: "memory");
    } else if (T + 1 < NT) {
      asm volatile("s_waitcnt vmcnt(0)" ::: "memory");
    }
    if (T + 1 < NT) __builtin_amdgcn_s_barrier();
  }

  // epilogue: 32x32 C/D map: col = lane&31, row = (reg&3)+8*(reg>>2)+4*(lane>>5)
  float scale = load_scale(amax_bits) * load_scale(amax_bits + 1);
  float* Cp = C + (size_t)(brow + wm * 128 + khalf * 4) * N_DIM +
              (bcol + wn * 64 + r5);
#pragma unroll
  for (int m = 0; m < 4; ++m)
#pragma unroll
    for (int r = 0; r < 16; ++r) {
      size_t ro = (size_t)(m * 32 + (r & 3) + 8 * (r >> 2)) * N_DIM;
#pragma unroll
      for (int n = 0; n < 2; ++n)
        Cp[ro + n * 32] = acc[m][n][r] * scale;
    }
}

// ----------------------------------------------------------------- launch ---
extern "C" void kernel_launch(void* const* d_in, const int* in_sizes, int n_in,
                              void* d_out, int out_size, void* d_ws,
                              size_t ws_size, hipStream_t stream) {
  const float* in1 = (const float*)d_in[0];
  const float* in2 = (const float*)d_in[1];
  float* out = (float*)d_out;
  unsigned char* ws = (unsigned char*)d_ws;

  const int R = in_sizes[0] / K_DIM;  // 16384
  const size_t qa_bytes = (size_t)R * K_DIM;
  const size_t qb_bytes = (size_t)N_DIM * K_DIM;
  const size_t need = 256 + qa_bytes + qb_bytes;
  if (ws_size < need) {
    fprintf(stderr, "kernel_launch: ws_size %zu < needed %zu\n", ws_size, need);
    return;
  }
  unsigned* amax = (unsigned*)ws;
  unsigned char* q1 = ws + 256;
  unsigned char* q2t = q1 + qa_bytes;

  hipMemsetAsync(ws, 0, 8, stream);
  amax_kernel<<<2048, 256, 0, stream>>>((const float4*)in1, in_sizes[0] / 4, amax);
  amax_kernel<<<1024, 256, 0, stream>>>((const float4*)in2, in_sizes[1] / 4, amax + 1);
  quant1_kernel<<<2048, 256, 0, stream>>>((const float4*)in1, (uint4*)q1, amax,
                                          in_sizes[0] / 16);
  quant2t_kernel<<<(K_DIM / 64) * (N_DIM / 64), 256, 0, stream>>>(in2, q2t, amax + 1);
  gemm_fp8_kernel<<<(R / 256) * (N_DIM / 256), 512, 0, stream>>>(q1, q2t, out, amax);
}